// Round 5
// baseline (11691.057 us; speedup 1.0000x reference)
//
#include <hip/hip_runtime.h>

#define NF 21
#define STR 24   // padded row stride (floats) so rows are 96B = 6x16B aligned

#define ATOMIC_ADD_F32(p, v) unsafeAtomicAdd((p), (v))

// Diagnostic: fills output with a recognizable sentinel if ws_size is insufficient.
__global__ __launch_bounds__(64) void sentinel_kernel(float* out, int m) {
    int i = blockIdx.x * 64 + threadIdx.x;
    if (i < m) out[i] = 0.109375f;
}

// deg[d] += ew[e] for each edge (self-loop +1 handled later as deg+1)
__global__ __launch_bounds__(256) void edge_deg_kernel(
    const int* __restrict__ ei, const float* __restrict__ ew,
    float* __restrict__ deg, int E) {
    int e = blockIdx.x * 256 + threadIdx.x;
    if (e >= E) return;
    int d = ei[E + e];
    ATOMIC_ADD_F32(deg + d, ew[e]);
}

// Layer 1 node kernel: dinv = rsqrt(deg+1); y = dinv*(x@W1); acc = y (self-loop term)
__global__ __launch_bounds__(256) void node_l1_kernel(
    const float* __restrict__ x, const float* __restrict__ deg,
    float* __restrict__ dinv, const float* __restrict__ W,
    float* __restrict__ y, float* __restrict__ acc, int n) {
    __shared__ float Ws[NF * NF];
    for (int i = threadIdx.x; i < NF * NF; i += 256) Ws[i] = W[i];
    __syncthreads();
    int i = blockIdx.x * 256 + threadIdx.x;
    if (i >= n) return;
    float di = rsqrtf(deg[i] + 1.0f);
    dinv[i] = di;
    float xr[NF];
    #pragma unroll
    for (int f = 0; f < NF; ++f) xr[f] = x[i * NF + f];
    #pragma unroll
    for (int j = 0; j < NF; ++j) {
        float v = 0.f;
        #pragma unroll
        for (int f = 0; f < NF; ++f) v += xr[f] * Ws[f * NF + j];
        float yv = di * v;
        y[i * STR + j]   = yv;
        acc[i * STR + j] = yv;
    }
}

// Edge scatter: acc[dst] += ew * y[src]   (21 features)
__global__ __launch_bounds__(256) void edge_msg_kernel(
    const int* __restrict__ ei, const float* __restrict__ ew,
    const float* __restrict__ y, float* __restrict__ acc, int E) {
    int e = blockIdx.x * 256 + threadIdx.x;
    if (e >= E) return;
    int s = ei[e];
    int d = ei[E + e];
    float w = ew[e];
    const float4* yv = (const float4*)(y + (size_t)s * STR);
    float4 v0 = yv[0], v1 = yv[1], v2 = yv[2], v3 = yv[3], v4 = yv[4];
    float v20 = y[(size_t)s * STR + 20];
    float* a = acc + (size_t)d * STR;
    ATOMIC_ADD_F32(a + 0,  w * v0.x); ATOMIC_ADD_F32(a + 1,  w * v0.y);
    ATOMIC_ADD_F32(a + 2,  w * v0.z); ATOMIC_ADD_F32(a + 3,  w * v0.w);
    ATOMIC_ADD_F32(a + 4,  w * v1.x); ATOMIC_ADD_F32(a + 5,  w * v1.y);
    ATOMIC_ADD_F32(a + 6,  w * v1.z); ATOMIC_ADD_F32(a + 7,  w * v1.w);
    ATOMIC_ADD_F32(a + 8,  w * v2.x); ATOMIC_ADD_F32(a + 9,  w * v2.y);
    ATOMIC_ADD_F32(a + 10, w * v2.z); ATOMIC_ADD_F32(a + 11, w * v2.w);
    ATOMIC_ADD_F32(a + 12, w * v3.x); ATOMIC_ADD_F32(a + 13, w * v3.y);
    ATOMIC_ADD_F32(a + 14, w * v3.z); ATOMIC_ADD_F32(a + 15, w * v3.w);
    ATOMIC_ADD_F32(a + 16, w * v4.x); ATOMIC_ADD_F32(a + 17, w * v4.y);
    ATOMIC_ADD_F32(a + 18, w * v4.z); ATOMIC_ADD_F32(a + 19, w * v4.w);
    ATOMIC_ADD_F32(a + 20, w * v20);
}

// Mid node kernel (layers 2,3): x = dinv*acc + b_prev; y = dinv*(x@W); acc = y
__global__ __launch_bounds__(256) void node_mid_kernel(
    const float* __restrict__ dinv, const float* __restrict__ bprev,
    const float* __restrict__ W,
    float* __restrict__ y, float* __restrict__ acc, int n) {
    __shared__ float Ws[NF * NF];
    __shared__ float bs[NF];
    for (int i = threadIdx.x; i < NF * NF; i += 256) Ws[i] = W[i];
    if (threadIdx.x < NF) bs[threadIdx.x] = bprev[threadIdx.x];
    __syncthreads();
    int i = blockIdx.x * 256 + threadIdx.x;
    if (i >= n) return;
    float di = dinv[i];
    float xr[NF];
    #pragma unroll
    for (int f = 0; f < NF; ++f) xr[f] = di * acc[i * STR + f] + bs[f];
    #pragma unroll
    for (int j = 0; j < NF; ++j) {
        float v = 0.f;
        #pragma unroll
        for (int f = 0; f < NF; ++f) v += xr[f] * Ws[f * NF + j];
        float yv = di * v;
        y[i * STR + j]   = yv;
        acc[i * STR + j] = yv;
    }
}

// Final node kernel: x = relu(dinv*acc + b3); pool sums/cnt per graph
__global__ __launch_bounds__(256) void node_final_kernel(
    const float* __restrict__ dinv, const float* __restrict__ b3,
    const int* __restrict__ batch, const float* __restrict__ acc,
    float* __restrict__ sums, float* __restrict__ cnt, int n) {
    __shared__ float bs[NF];
    if (threadIdx.x < NF) bs[threadIdx.x] = b3[threadIdx.x];
    __syncthreads();
    int i = blockIdx.x * 256 + threadIdx.x;
    if (i >= n) return;
    float di = dinv[i];
    int g = batch[i];
    #pragma unroll
    for (int f = 0; f < NF; ++f) {
        float v = di * acc[i * STR + f] + bs[f];
        v = fmaxf(v, 0.f);
        ATOMIC_ADD_F32(sums + g * NF + f, v);
    }
    ATOMIC_ADD_F32(cnt + g, 1.0f);
}

// MLP + softmax: one block per graph; fp32 output
__global__ __launch_bounds__(256) void mlp_kernel(
    const float* __restrict__ sums, const float* __restrict__ cnt,
    const float* __restrict__ Wp,  const float* __restrict__ bp,
    const float* __restrict__ Wf1, const float* __restrict__ bf1,
    const float* __restrict__ Wf2, const float* __restrict__ bf2,
    const float* __restrict__ Wo,  const float* __restrict__ bo,
    float* __restrict__ out) {
    int g = blockIdx.x;
    int t = threadIdx.x;
    __shared__ float xr[NF], h1[128], h2[256], h3[64];
    if (t < NF) xr[t] = sums[g * NF + t] / fmaxf(cnt[g], 1.0f);
    __syncthreads();
    if (t < 128) {
        float v = bp[t];
        #pragma unroll
        for (int f = 0; f < NF; ++f) v += xr[f] * Wp[f * 128 + t];
        h1[t] = v >= 0.f ? v : 0.01f * v;
    }
    __syncthreads();
    {
        float v = bf1[t];
        for (int k = 0; k < 128; ++k) v += h1[k] * Wf1[k * 256 + t];
        h2[t] = v >= 0.f ? v : 0.01f * v;
    }
    __syncthreads();
    if (t < 64) {
        float v = bf2[t];
        for (int k = 0; k < 256; ++k) v += h2[k] * Wf2[k * 64 + t];
        h3[t] = v >= 0.f ? v : 0.01f * v;
    }
    __syncthreads();
    if (t == 0) {
        float lg[5];
        float m = -1e30f;
        for (int j = 0; j < 5; ++j) {
            float v = bo[j];
            for (int k = 0; k < 64; ++k) v += h3[k] * Wo[k * 5 + j];
            lg[j] = v;
            m = fmaxf(m, v);
        }
        float den = 0.f;
        for (int j = 0; j < 5; ++j) { lg[j] = __expf(lg[j] - m); den += lg[j]; }
        for (int j = 0; j < 5; ++j) out[g * 5 + j] = lg[j] / den;
    }
}

extern "C" void kernel_launch(void* const* d_in, const int* in_sizes, int n_in,
                              void* d_out, int out_size, void* d_ws, size_t ws_size,
                              hipStream_t stream) {
    const float* x     = (const float*)d_in[0];
    const int*   ei    = (const int*)d_in[1];
    const float* ew    = (const float*)d_in[2];
    const int*   batch = (const int*)d_in[3];
    const float* W1 = (const float*)d_in[4];
    const float* b1 = (const float*)d_in[5];
    const float* W2 = (const float*)d_in[6];
    const float* b2 = (const float*)d_in[7];
    const float* W3 = (const float*)d_in[8];
    const float* b3 = (const float*)d_in[9];
    const float* Wp  = (const float*)d_in[10];
    const float* bp  = (const float*)d_in[11];
    const float* Wf1 = (const float*)d_in[12];
    const float* bf1 = (const float*)d_in[13];
    const float* Wf2 = (const float*)d_in[14];
    const float* bf2 = (const float*)d_in[15];
    const float* Wo  = (const float*)d_in[16];
    const float* bo  = (const float*)d_in[17];

    const int n = in_sizes[0] / NF;   // 100000
    const int E = in_sizes[2];        // 3200000
    const int B = out_size / 5;       // 64

    // Workspace layout (floats): deg[n] dinv[n] y[n*STR] acc[n*STR] sums[B*NF] cnt[B]
    const size_t need_floats = (size_t)2 * n + (size_t)2 * n * STR + (size_t)B * NF + B;
    if (ws_size < need_floats * sizeof(float)) {
        sentinel_kernel<<<(out_size + 63) / 64, 64, 0, stream>>>((float*)d_out, out_size);
        return;
    }

    float* ws   = (float*)d_ws;
    float* deg  = ws;                       // n
    float* dinv = ws + n;                   // n
    float* y    = ws + 2 * n;               // n*STR (96B rows, 16B aligned)
    float* acc  = ws + 2 * n + n * STR;     // n*STR
    float* sums = ws + 2 * n + 2 * n * STR; // B*NF
    float* cnt  = sums + B * NF;            // B

    hipMemsetAsync(deg, 0, (size_t)n * sizeof(float), stream);
    hipMemsetAsync(sums, 0, (size_t)(B * NF + B) * sizeof(float), stream);

    int nb_e = (E + 255) / 256;
    int nb_n = (n + 255) / 256;

    edge_deg_kernel<<<nb_e, 256, 0, stream>>>(ei, ew, deg, E);
    node_l1_kernel<<<nb_n, 256, 0, stream>>>(x, deg, dinv, W1, y, acc, n);
    edge_msg_kernel<<<nb_e, 256, 0, stream>>>(ei, ew, y, acc, E);
    node_mid_kernel<<<nb_n, 256, 0, stream>>>(dinv, b1, W2, y, acc, n);
    edge_msg_kernel<<<nb_e, 256, 0, stream>>>(ei, ew, y, acc, E);
    node_mid_kernel<<<nb_n, 256, 0, stream>>>(dinv, b2, W3, y, acc, n);
    edge_msg_kernel<<<nb_e, 256, 0, stream>>>(ei, ew, y, acc, E);
    node_final_kernel<<<nb_n, 256, 0, stream>>>(dinv, b3, batch, acc, sums, cnt, n);
    mlp_kernel<<<B, 256, 0, stream>>>(sums, cnt, Wp, bp, Wf1, bf1, Wf2, bf2, Wo, bo,
                                      (float*)d_out);
}

// Round 6
// 1106.131 us; speedup vs baseline: 10.5693x; 10.5693x over previous
//
#include <hip/hip_runtime.h>

#define NF 21
#define STR 24      // padded row stride (floats), 96B rows
#define BN 12       // nodes per block in gather kernels (12*21 = 252 lanes used)
#define SCAN_T 1024

#define ATOMIC_ADD_F32(p, v) unsafeAtomicAdd((p), (v))

// Diagnostic: fills output with a recognizable sentinel if ws_size is insufficient.
__global__ __launch_bounds__(64) void sentinel_kernel(float* out, int m) {
    int i = blockIdx.x * 64 + threadIdx.x;
    if (i < m) out[i] = 0.109375f;
}

// --- CSR build ---------------------------------------------------------------

// counts[dst]++ per edge
__global__ __launch_bounds__(256) void hist_kernel(
    const int* __restrict__ ei, int* __restrict__ counts, int E) {
    int e = blockIdx.x * 256 + threadIdx.x;
    if (e >= E) return;
    atomicAdd(&counts[ei[E + e]], 1);
}

// single-block exclusive scan in-place over data[0..n)
__global__ __launch_bounds__(SCAN_T) void scan_kernel(int* __restrict__ data, int n) {
    __shared__ int sd[SCAN_T];
    int t = threadIdx.x;
    int chunk = (n + SCAN_T - 1) / SCAN_T;
    int base = t * chunk;
    int s = 0;
    for (int i = 0; i < chunk; ++i) { int idx = base + i; if (idx < n) s += data[idx]; }
    sd[t] = s;
    __syncthreads();
    for (int off = 1; off < SCAN_T; off <<= 1) {
        int v = (t >= off) ? sd[t - off] : 0;
        __syncthreads();
        sd[t] += v;
        __syncthreads();
    }
    int run = sd[t] - s;  // exclusive prefix of this thread's chunk
    for (int i = 0; i < chunk; ++i) {
        int idx = base + i;
        if (idx < n) { int v = data[idx]; data[idx] = run; run += v; }
    }
}

// scatter edges into CSR; rowptr[d] bumps from start(d) to end(d).
// After this kernel: segment(d) = [ d==0 ? 0 : rowptr[d-1], rowptr[d] ).
__global__ __launch_bounds__(256) void scatter_kernel(
    const int* __restrict__ ei, const float* __restrict__ ew,
    int* __restrict__ rowptr, int2* __restrict__ csr, int E) {
    int e = blockIdx.x * 256 + threadIdx.x;
    if (e >= E) return;
    int s = ei[e], d = ei[E + e];
    int pos = atomicAdd(&rowptr[d], 1);
    csr[pos] = make_int2(s, __float_as_int(ew[e]));
}

// --- Layer 1: deg from CSR, dinv, y = dinv*(x@W1) ---------------------------
__global__ __launch_bounds__(256) void node_l1_kernel(
    const float* __restrict__ x, const int* __restrict__ rowptr,
    const int2* __restrict__ csr, const float* __restrict__ W,
    float* __restrict__ dinv, float* __restrict__ y, int n) {
    __shared__ float Ws[NF * NF];
    for (int i = threadIdx.x; i < NF * NF; i += 256) Ws[i] = W[i];
    __syncthreads();
    int i = blockIdx.x * 256 + threadIdx.x;
    if (i >= n) return;
    int start = (i == 0) ? 0 : rowptr[i - 1], end = rowptr[i];
    float deg = 0.f;
    for (int e = start; e < end; ++e) deg += __int_as_float(csr[e].y);
    float di = rsqrtf(deg + 1.0f);
    dinv[i] = di;
    float xr[NF];
    #pragma unroll
    for (int f = 0; f < NF; ++f) xr[f] = x[i * NF + f];
    #pragma unroll
    for (int j = 0; j < NF; ++j) {
        float v = 0.f;
        #pragma unroll
        for (int f = 0; f < NF; ++f) v += xr[f] * Ws[f * NF + j];
        y[(size_t)i * STR + j] = di * v;
    }
}

// --- Fused GCN layer (layers 2,3): gather + prev-layer finish + matvec ------
// h = dinv*(gather(yin) + yin[d]) + bprev ; yout = dinv*(h @ W)
__global__ __launch_bounds__(256) void layer_kernel(
    const int* __restrict__ rowptr, const int2* __restrict__ csr,
    const float* __restrict__ dinv, const float* __restrict__ bprev,
    const float* __restrict__ W,
    const float* __restrict__ yin, float* __restrict__ yout, int n) {
    __shared__ float Ws[NF * NF];
    __shared__ float bsh[NF];
    __shared__ float xr[BN][NF];
    for (int i = threadIdx.x; i < NF * NF; i += 256) Ws[i] = W[i];
    if (threadIdx.x < NF) bsh[threadIdx.x] = bprev[threadIdx.x];
    __syncthreads();
    int t = threadIdx.x;
    int nd = t / NF, f = t - nd * NF;
    int d = blockIdx.x * BN + nd;
    bool act = (nd < BN) && (d < n);
    float di = 0.f;
    if (act) {
        di = dinv[d];
        float g = 0.f;
        int start = (d == 0) ? 0 : rowptr[d - 1], end = rowptr[d];
        for (int e = start; e < end; ++e) {
            int2 c = csr[e];  // broadcast across the 21-lane group
            g += __int_as_float(c.y) * yin[(size_t)c.x * STR + f];  // 84B contiguous per group
        }
        xr[nd][f] = di * (g + yin[(size_t)d * STR + f]) + bsh[f];
    }
    __syncthreads();
    if (act) {
        float v = 0.f;
        #pragma unroll
        for (int k = 0; k < NF; ++k) v += xr[nd][k] * Ws[k * NF + f];
        yout[(size_t)d * STR + f] = di * v;
    }
}

// --- Final: gather + relu, write h3 (no matvec) ------------------------------
__global__ __launch_bounds__(256) void final_gather_kernel(
    const int* __restrict__ rowptr, const int2* __restrict__ csr,
    const float* __restrict__ dinv, const float* __restrict__ b3,
    const float* __restrict__ yin, float* __restrict__ hout, int n) {
    __shared__ float bsh[NF];
    if (threadIdx.x < NF) bsh[threadIdx.x] = b3[threadIdx.x];
    __syncthreads();
    int t = threadIdx.x;
    int nd = t / NF, f = t - nd * NF;
    int d = blockIdx.x * BN + nd;
    if (nd >= BN || d >= n) return;  // no barriers after this point
    float g = 0.f;
    int start = (d == 0) ? 0 : rowptr[d - 1], end = rowptr[d];
    for (int e = start; e < end; ++e) {
        int2 c = csr[e];
        g += __int_as_float(c.y) * yin[(size_t)c.x * STR + f];
    }
    float h = dinv[d] * (g + yin[(size_t)d * STR + f]) + bsh[f];
    hout[(size_t)d * STR + f] = fmaxf(h, 0.f);
}

// --- Mean-pool: one block per graph, batch is sorted → binary-search bounds --
__global__ __launch_bounds__(256) void pool_kernel(
    const float* __restrict__ h, const int* __restrict__ batch,
    float* __restrict__ sums, float* __restrict__ cnt, int n) {
    int g = blockIdx.x;
    __shared__ int bounds[2];
    if (threadIdx.x == 0) {
        int lo = 0, hi = n;
        while (lo < hi) { int mid = (lo + hi) >> 1; if (batch[mid] < g) lo = mid + 1; else hi = mid; }
        bounds[0] = lo;
        lo = 0; hi = n;
        while (lo < hi) { int mid = (lo + hi) >> 1; if (batch[mid] < g + 1) lo = mid + 1; else hi = mid; }
        bounds[1] = lo;
    }
    __syncthreads();
    int lo = bounds[0], hi = bounds[1];
    float acc[NF];
    #pragma unroll
    for (int f = 0; f < NF; ++f) acc[f] = 0.f;
    for (int i = lo + threadIdx.x; i < hi; i += 256) {
        #pragma unroll
        for (int f = 0; f < NF; ++f) acc[f] += h[(size_t)i * STR + f];
    }
    __shared__ float red[256];
    for (int f = 0; f < NF; ++f) {
        red[threadIdx.x] = acc[f];
        __syncthreads();
        for (int s2 = 128; s2 > 0; s2 >>= 1) {
            if (threadIdx.x < s2) red[threadIdx.x] += red[threadIdx.x + s2];
            __syncthreads();
        }
        if (threadIdx.x == 0) sums[g * NF + f] = red[0];
        __syncthreads();
    }
    if (threadIdx.x == 0) cnt[g] = (float)(hi - lo);
}

// --- MLP + softmax: one block per graph; fp32 output -------------------------
__global__ __launch_bounds__(256) void mlp_kernel(
    const float* __restrict__ sums, const float* __restrict__ cnt,
    const float* __restrict__ Wp,  const float* __restrict__ bp,
    const float* __restrict__ Wf1, const float* __restrict__ bf1,
    const float* __restrict__ Wf2, const float* __restrict__ bf2,
    const float* __restrict__ Wo,  const float* __restrict__ bo,
    float* __restrict__ out) {
    int g = blockIdx.x;
    int t = threadIdx.x;
    __shared__ float xr[NF], h1[128], h2[256], h3[64];
    if (t < NF) xr[t] = sums[g * NF + t] / fmaxf(cnt[g], 1.0f);
    __syncthreads();
    if (t < 128) {
        float v = bp[t];
        #pragma unroll
        for (int f = 0; f < NF; ++f) v += xr[f] * Wp[f * 128 + t];
        h1[t] = v >= 0.f ? v : 0.01f * v;
    }
    __syncthreads();
    {
        float v = bf1[t];
        for (int k = 0; k < 128; ++k) v += h1[k] * Wf1[k * 256 + t];
        h2[t] = v >= 0.f ? v : 0.01f * v;
    }
    __syncthreads();
    if (t < 64) {
        float v = bf2[t];
        for (int k = 0; k < 256; ++k) v += h2[k] * Wf2[k * 64 + t];
        h3[t] = v >= 0.f ? v : 0.01f * v;
    }
    __syncthreads();
    if (t == 0) {
        float lg[5];
        float m = -1e30f;
        for (int j = 0; j < 5; ++j) {
            float v = bo[j];
            for (int k = 0; k < 64; ++k) v += h3[k] * Wo[k * 5 + j];
            lg[j] = v;
            m = fmaxf(m, v);
        }
        float den = 0.f;
        for (int j = 0; j < 5; ++j) { lg[j] = __expf(lg[j] - m); den += lg[j]; }
        for (int j = 0; j < 5; ++j) out[g * 5 + j] = lg[j] / den;
    }
}

extern "C" void kernel_launch(void* const* d_in, const int* in_sizes, int n_in,
                              void* d_out, int out_size, void* d_ws, size_t ws_size,
                              hipStream_t stream) {
    const float* x     = (const float*)d_in[0];
    const int*   ei    = (const int*)d_in[1];
    const float* ew    = (const float*)d_in[2];
    const int*   batch = (const int*)d_in[3];
    const float* W1 = (const float*)d_in[4];
    const float* b1 = (const float*)d_in[5];
    const float* W2 = (const float*)d_in[6];
    const float* b2 = (const float*)d_in[7];
    const float* W3 = (const float*)d_in[8];
    const float* b3 = (const float*)d_in[9];
    const float* Wp  = (const float*)d_in[10];
    const float* bp  = (const float*)d_in[11];
    const float* Wf1 = (const float*)d_in[12];
    const float* bf1 = (const float*)d_in[13];
    const float* Wf2 = (const float*)d_in[14];
    const float* bf2 = (const float*)d_in[15];
    const float* Wo  = (const float*)d_in[16];
    const float* bo  = (const float*)d_in[17];

    const int n = in_sizes[0] / NF;   // 100000
    const int E = in_sizes[2];        // 3200000
    const int B = out_size / 5;       // 64

    // ws layout (4B units): csr int2[E] | rowptr[n] | dinv[n] | yA[n*STR] | yB[n*STR] | sums[B*NF] | cnt[B]
    const size_t need_words = (size_t)2 * E + 2 * (size_t)n + 2 * (size_t)n * STR
                            + (size_t)B * NF + B;
    if (ws_size < need_words * 4) {
        sentinel_kernel<<<(out_size + 63) / 64, 64, 0, stream>>>((float*)d_out, out_size);
        return;
    }

    int2*  csr    = (int2*)d_ws;
    int*   rowptr = (int*)d_ws + (size_t)2 * E;
    float* dinv   = (float*)((int*)d_ws + (size_t)2 * E + n);
    float* yA     = dinv + n;
    float* yB     = yA + (size_t)n * STR;
    float* sums   = yB + (size_t)n * STR;
    float* cnt    = sums + (size_t)B * NF;

    hipMemsetAsync(rowptr, 0, (size_t)n * sizeof(int), stream);

    int nb_e = (E + 255) / 256;
    int nb_n = (n + 255) / 256;
    int nb_g = (n + BN - 1) / BN;

    hist_kernel<<<nb_e, 256, 0, stream>>>(ei, rowptr, E);
    scan_kernel<<<1, SCAN_T, 0, stream>>>(rowptr, n);
    scatter_kernel<<<nb_e, 256, 0, stream>>>(ei, ew, rowptr, csr, E);

    node_l1_kernel<<<nb_n, 256, 0, stream>>>(x, rowptr, csr, W1, dinv, yA, n);
    layer_kernel<<<nb_g, 256, 0, stream>>>(rowptr, csr, dinv, b1, W2, yA, yB, n);
    layer_kernel<<<nb_g, 256, 0, stream>>>(rowptr, csr, dinv, b2, W3, yB, yA, n);
    final_gather_kernel<<<nb_g, 256, 0, stream>>>(rowptr, csr, dinv, b3, yA, yB, n);
    pool_kernel<<<B, 256, 0, stream>>>(yB, batch, sums, cnt, n);
    mlp_kernel<<<B, 256, 0, stream>>>(sums, cnt, Wp, bp, Wf1, bf1, Wf2, bf2, Wo, bo,
                                      (float*)d_out);
}